// Round 11
// baseline (397.700 us; speedup 1.0000x reference)
//
#include <hip/hip_runtime.h>
#include <math.h>

#define HH 512
#define WW 512
#define BB 32
#define KK 8
#define SPLIT 8
#define NBLK (BB * KK * SPLIT)      // 2048 blocks
#define CHUNK ((HH * WW) / SPLIT)   // 32768 floats per block
#define BLOCK 256
#define MLP 8                        // independent load+max chains per thread

typedef unsigned long long u64;
typedef unsigned int u32;
typedef float f4 __attribute__((ext_vector_type(4)));

// Monotone float->u32 key: a > b  <=>  fkey(a) > fkey(b)
__device__ __forceinline__ u32 fkey(float f) {
    u32 b = __float_as_uint(f);
    u32 m = (u32)((int)b >> 31);
    return b ^ (m | 0x80000000u);
}

// Kernel 1: per-(b,k)-segment argmax.
// Hot loop: quad-max (v_max3) + strict-> (val, quad-idx) update = ~1.5 VALU/elem.
// Index-within-quad recovered AFTER the scan by reloading the one winning quad.
__global__ __launch_bounds__(BLOCK) void argmax_partial(
    const float* __restrict__ hm, u64* __restrict__ pbest)
{
    const int blk = blockIdx.x;
    const int seg = blk % SPLIT;
    const int bk  = blk / SPLIT;
    const int t   = threadIdx.x;

    const f4* base =
        reinterpret_cast<const f4*>(hm + (size_t)bk * (HH * WW) + (size_t)seg * CHUNK);

    const int n4 = CHUNK / 4;  // 8192 quads per block; 32 per thread

    float bv[MLP];   // best quad-max per chain
    int   bq[MLP];   // its quad index (within segment's f4 array)
#pragma unroll
    for (int j = 0; j < MLP; ++j) { bv[j] = -INFINITY; bq[j] = 0; }

    for (int b0 = 0; b0 < n4; b0 += MLP * BLOCK) {   // 4 iterations
        f4 v[MLP];
#pragma unroll
        for (int j = 0; j < MLP; ++j)
            v[j] = __builtin_nontemporal_load(&base[b0 + j * BLOCK + t]);
#pragma unroll
        for (int j = 0; j < MLP; ++j) {
            const float qm = fmaxf(fmaxf(v[j].x, v[j].y), fmaxf(v[j].z, v[j].w));
            const int   qi = b0 + j * BLOCK + t;
            // strict '>': earliest quad wins ties within a chain
            if (qm > bv[j]) { bv[j] = qm; bq[j] = qi; }
        }
    }

    // merge chains: value desc, then quad-idx asc (chains interleave indices)
    float tv = bv[0]; int tq = bq[0];
#pragma unroll
    for (int j = 1; j < MLP; ++j) {
        if (bv[j] > tv || (bv[j] == tv && bq[j] < tq)) { tv = bv[j]; tq = bq[j]; }
    }

    // recover intra-quad position: reload winning quad (L2-hot), first-match cascade
    const f4 q = base[tq];
    int iq = 3;
    if (q.z == tv) iq = 2;
    if (q.y == tv) iq = 1;
    if (q.x == tv) iq = 0;
    const u32 fi = (u32)(seg * CHUNK + tq * 4 + iq);   // flat index in heatmap

    // packed (key, ~idx): associative max, ties -> smaller idx
    u64 tb = ((u64)fkey(tv) << 32) | (u32)~fi;

    __shared__ u64 sb[BLOCK];
    sb[t] = tb;
    __syncthreads();
    for (int s = BLOCK / 2; s > 0; s >>= 1) {
        if (t < s) { u64 o = sb[t + s]; if (o > sb[t]) sb[t] = o; }
        __syncthreads();
    }
    if (t == 0) pbest[blk] = sb[0];
}

// Kernel 2: one block, 256 threads; thread t = (b,k) pair.
__global__ __launch_bounds__(BLOCK) void finalize(
    const u64* __restrict__ pbest,
    const float* __restrict__ gt,
    const float* __restrict__ m0, const float* __restrict__ m1,
    const float* __restrict__ m2, float* __restrict__ out)
{
    const int t = threadIdx.x;        // t = b*K + k
    const int b = t / KK;

    u64 best = 0ull;
    for (int s = 0; s < SPLIT; ++s) {
        u64 p = pbest[t * SPLIT + s];
        if (p > best) best = p;       // packed max: ties -> smaller idx
    }
    const int fi = (int)(~(u32)(best & 0xFFFFFFFFu));   // flat argmax index

    const float x = (float)(fi % WW) * (1.0f / (WW - 1));
    const float y = (float)(fi / WW) * (1.0f / (HH - 1));

    // reference: ix = floor(clip(x,0,511)) in {0,1}; same for y
    const int ix = (int)floorf(fminf(fmaxf(x, 0.0f), 511.0f));
    const int iy = (int)floorf(fminf(fmaxf(y, 0.0f), 511.0f));
    const float fx = fabsf(x - (float)ix);
    const float fy = fabsf(y - (float)iy);

    // reference gathers padding_mask[b, ix, iy] (x-coord indexes dim-1)
    const size_t mo = (size_t)b * (HH * WW) + (size_t)ix * WW + (size_t)iy;
    const float g0 = m0[mo];
    const float g1 = m1[mo];
    const float g2 = m2[mo];

    const float gtx = gt[t * 2 + 0];
    const float gty = gt[t * 2 + 1];

    // |x-gtx|+|y-gty| + 3*10*(fx+fy) + 10*10*((1-g0)+(1-g1)+(1-g2))
    float loss = fabsf(x - gtx) + fabsf(y - gty)
               + 30.0f  * (fx + fy)
               + 100.0f * (3.0f - g0 - g1 - g2);

    __shared__ float ss[BLOCK];
    ss[t] = loss;
    __syncthreads();
    for (int s = BLOCK / 2; s > 0; s >>= 1) {
        if (t < s) ss[t] += ss[t + s];
        __syncthreads();
    }
    if (t == 0) out[0] = ss[0];
}

extern "C" void kernel_launch(void* const* d_in, const int* in_sizes, int n_in,
                              void* d_out, int out_size, void* d_ws, size_t ws_size,
                              hipStream_t stream)
{
    const float* hm = (const float*)d_in[0];   // (32, 8, 512, 512) f32
    const float* gt = (const float*)d_in[1];   // (32, 8, 2) f32
    const float* m0 = (const float*)d_in[2];   // (32, 512, 512) f32
    const float* m1 = (const float*)d_in[3];
    const float* m2 = (const float*)d_in[4];

    u64* pbest = (u64*)d_ws;                   // 2048 * 8 B = 16 KB

    argmax_partial<<<NBLK, BLOCK, 0, stream>>>(hm, pbest);
    finalize<<<1, BLOCK, 0, stream>>>(pbest, gt, m0, m1, m2, (float*)d_out);
}